// Round 3
// baseline (380.089 us; speedup 1.0000x reference)
//
#include <hip/hip_runtime.h>
#include <math.h>

__device__ __forceinline__ float leaky(float v){ return v > 0.f ? v : 0.2f*v; }

__device__ __forceinline__ float wredsum(float v){
  #pragma unroll
  for (int o=32;o>0;o>>=1) v += __shfl_xor(v,o,64);
  return v;
}

// ---------------- graph CSR build (by dst) ----------------
__global__ void k_zero(int* p, int n){
  int i = blockIdx.x*blockDim.x + threadIdx.x;
  if (i < n) p[i] = 0;
}

__global__ void k_hist(const int* __restrict__ dst, int* __restrict__ deg, int E){
  int i = blockIdx.x*blockDim.x + threadIdx.x;
  if (i < E) atomicAdd(&deg[dst[i]], 1);
}

__global__ __launch_bounds__(1024) void k_scan(const int* __restrict__ deg, int* __restrict__ off,
                                               int* __restrict__ cur, int N){
  __shared__ int part[1024];
  int t = threadIdx.x;
  int chunk = (N + 1023) >> 10;
  int c0 = t * chunk;
  int sum = 0;
  for (int i=0;i<chunk;i++){ int idx=c0+i; if (idx < N) sum += deg[idx]; }
  part[t] = sum;
  __syncthreads();
  for (int o=1;o<1024;o<<=1){
    int v = (t >= o) ? part[t-o] : 0;
    __syncthreads();
    part[t] += v;
    __syncthreads();
  }
  int run = part[t] - sum;   // exclusive prefix of this chunk
  for (int i=0;i<chunk;i++){
    int idx = c0+i;
    if (idx < N){ off[idx] = run; cur[idx] = run; run += deg[idx]; }
  }
  if (t == 1023) off[N] = part[1023];
}

__global__ void k_scatter(const int* __restrict__ src, const int* __restrict__ dst,
                          int* __restrict__ cur, int* __restrict__ srcs, int E){
  int i = blockIdx.x*blockDim.x + threadIdx.x;
  if (i < E){ int p = atomicAdd(&cur[dst[i]], 1); srcs[p] = src[i]; }
}

// ---------------- fp32 GEMM, K=64 fixed, 64x64 tiles, optional fused attn-coef ----------------
__global__ __launch_bounds__(256) void k_gemm64(const float* __restrict__ A, const float* __restrict__ B,
                                                float* __restrict__ C, int M, int Nn,
                                                const float* __restrict__ al, const float* __restrict__ ar,
                                                float* __restrict__ el, float* __restrict__ er, int H){
  __shared__ __align__(16) float As[64][68];
  __shared__ __align__(16) float Bs[64][68];
  const int m0 = blockIdx.x*64, c0 = blockIdx.y*64;
  const int tid = threadIdx.x;
  #pragma unroll
  for (int q=0;q<4;q++){
    int lin = tid + q*256;
    int r = lin >> 4, c4 = (lin & 15) << 2;
    float4 va = make_float4(0.f,0.f,0.f,0.f);
    if (m0 + r < M) va = *reinterpret_cast<const float4*>(A + (size_t)(m0+r)*64 + c4);
    *reinterpret_cast<float4*>(&As[r][c4]) = va;
    float4 vb = *reinterpret_cast<const float4*>(B + (size_t)r*Nn + c0 + c4);
    *reinterpret_cast<float4*>(&Bs[r][c4]) = vb;
  }
  __syncthreads();
  const int tx = tid & 15, ty = tid >> 4;
  float acc[4][4] = {};
  #pragma unroll
  for (int k=0;k<64;k+=4){
    float av[4][4], bv[4][4];
    #pragma unroll
    for (int i=0;i<4;i++){
      float4 t = *reinterpret_cast<const float4*>(&As[ty*4+i][k]);
      av[i][0]=t.x; av[i][1]=t.y; av[i][2]=t.z; av[i][3]=t.w;
    }
    #pragma unroll
    for (int kk=0;kk<4;kk++){
      float4 t = *reinterpret_cast<const float4*>(&Bs[k+kk][tx*4]);
      bv[kk][0]=t.x; bv[kk][1]=t.y; bv[kk][2]=t.z; bv[kk][3]=t.w;
    }
    #pragma unroll
    for (int kk=0;kk<4;kk++)
      #pragma unroll
      for (int i=0;i<4;i++)
        #pragma unroll
        for (int j=0;j<4;j++)
          acc[i][j] += av[i][kk]*bv[kk][j];
  }
  #pragma unroll
  for (int i=0;i<4;i++){
    int row = m0 + ty*4 + i;
    if (row < M){
      float4 v = make_float4(acc[i][0],acc[i][1],acc[i][2],acc[i][3]);
      *reinterpret_cast<float4*>(C + (size_t)row*Nn + c0 + tx*4) = v;
    }
  }
  if (el){
    const int h = blockIdx.y;
    float alv[4], arv[4];
    #pragma unroll
    for (int j=0;j<4;j++){ alv[j] = al[c0 + tx*4 + j]; arv[j] = ar[c0 + tx*4 + j]; }
    #pragma unroll
    for (int i=0;i<4;i++){
      float pl = acc[i][0]*alv[0] + acc[i][1]*alv[1] + acc[i][2]*alv[2] + acc[i][3]*alv[3];
      float pr = acc[i][0]*arv[0] + acc[i][1]*arv[1] + acc[i][2]*arv[2] + acc[i][3]*arv[3];
      #pragma unroll
      for (int o=8;o>0;o>>=1){ pl += __shfl_xor(pl,o,16); pr += __shfl_xor(pr,o,16); }
      int row = m0 + ty*4 + i;
      if (tx == 0 && row < M){
        el[(size_t)row*H + h] = pl;
        er[(size_t)row*H + h] = pr;
      }
    }
  }
}

// layer2 coef: el[n] = sum_{128} f2[n,:]*al2 (one wave per node)
__global__ __launch_bounds__(256) void k_coef2(const float* __restrict__ f2, const float* __restrict__ al,
                                               const float* __restrict__ ar, float* __restrict__ el,
                                               float* __restrict__ er, int N){
  int n = blockIdx.x*4 + (threadIdx.x>>6);
  int lane = threadIdx.x & 63;
  if (n >= N) return;
  float x0 = f2[(size_t)n*128+lane], x1 = f2[(size_t)n*128+64+lane];
  float pl = wredsum(x0*al[lane] + x1*al[64+lane]);
  float pr = wredsum(x0*ar[lane] + x1*ar[64+lane]);
  if (lane==0){ el[n]=pl; er[n]=pr; }
}

// ---------------- layer1 edge aggregation ----------------
// One wave per node. Pass A: plain max-reduce. Pass B: the wave consumes the whole
// contiguous 2560B f1 row per edge via 3 dwordx4 loads; element s*256+4*lane+j is
// (head 4s+(lane>>4), d=(4*lane+j)&63). Head weights broadcast via bpermute.
// Head-sum epilogue through per-wave LDS.
__global__ __launch_bounds__(256) void k_edge1(const float* __restrict__ f1, const float* __restrict__ el,
                                               const float* __restrict__ er, const int* __restrict__ off,
                                               const int* __restrict__ srcs, const float* __restrict__ b1,
                                               float* __restrict__ hout, int N){
  __shared__ float sh[4*640];
  const int wid  = threadIdx.x >> 6;
  const int lane = threadIdx.x & 63;
  const int n = blockIdx.x*4 + wid;
  if (n >= N) return;
  const int beg = off[n], end = off[n+1];
  const bool hl = lane < 10;
  const float erh = hl ? er[n*10+lane] : 0.f;
  const int hm0 = lane >> 4;        // head for slot 0
  const int hm1 = 4 + (lane >> 4);  // slot 1
  const int hm2 = 8 + (lane >> 4);  // slot 2 (valid lanes < 32)
  // pass A: m_h = leaky(max_e el[src,h] + er_h)
  float m0=-INFINITY, m1=-INFINITY, m2=-INFINITY, m3=-INFINITY;
  int e = beg;
  for (; e+3<end; e+=4){
    int s0=srcs[e], s1=srcs[e+1], s2=srcs[e+2], s3=srcs[e+3];
    if (hl){
      m0 = fmaxf(m0, el[s0*10+lane]);
      m1 = fmaxf(m1, el[s1*10+lane]);
      m2 = fmaxf(m2, el[s2*10+lane]);
      m3 = fmaxf(m3, el[s3*10+lane]);
    }
  }
  for (; e<end; ++e) if (hl) m0 = fmaxf(m0, el[srcs[e]*10+lane]);
  const float m = leaky(fmaxf(fmaxf(m0,m1),fmaxf(m2,m3)) + erh);
  // pass B: fused exp + denom + whole-row weighted accumulate
  float s = 0.f;
  float acc0[4] = {0.f,0.f,0.f,0.f}, acc1[4] = {0.f,0.f,0.f,0.f}, acc2[4] = {0.f,0.f,0.f,0.f};
  e = beg;
  for (; e+1<end; e+=2){
    const int s0 = srcs[e], s1 = srcs[e+1];
    float w0 = 0.f, w1 = 0.f;
    if (hl){
      w0 = __expf(leaky(el[s0*10+lane]+erh) - m);
      w1 = __expf(leaky(el[s1*10+lane]+erh) - m);
      s += w0 + w1;
    }
    const float* r0 = f1 + (size_t)s0*640;
    const float* r1 = f1 + (size_t)s1*640;
    float4 v00 = *reinterpret_cast<const float4*>(r0 + 4*lane);
    float4 v01 = *reinterpret_cast<const float4*>(r0 + 256 + 4*lane);
    float4 v10 = *reinterpret_cast<const float4*>(r1 + 4*lane);
    float4 v11 = *reinterpret_cast<const float4*>(r1 + 256 + 4*lane);
    float4 v02 = make_float4(0.f,0.f,0.f,0.f), v12 = make_float4(0.f,0.f,0.f,0.f);
    if (lane < 32){
      v02 = *reinterpret_cast<const float4*>(r0 + 512 + 4*lane);
      v12 = *reinterpret_cast<const float4*>(r1 + 512 + 4*lane);
    }
    float w0s0 = __shfl(w0,hm0,64), w0s1 = __shfl(w0,hm1,64), w0s2 = __shfl(w0,hm2,64);
    float w1s0 = __shfl(w1,hm0,64), w1s1 = __shfl(w1,hm1,64), w1s2 = __shfl(w1,hm2,64);
    acc0[0] += w0s0*v00.x + w1s0*v10.x;  acc0[1] += w0s0*v00.y + w1s0*v10.y;
    acc0[2] += w0s0*v00.z + w1s0*v10.z;  acc0[3] += w0s0*v00.w + w1s0*v10.w;
    acc1[0] += w0s1*v01.x + w1s1*v11.x;  acc1[1] += w0s1*v01.y + w1s1*v11.y;
    acc1[2] += w0s1*v01.z + w1s1*v11.z;  acc1[3] += w0s1*v01.w + w1s1*v11.w;
    acc2[0] += w0s2*v02.x + w1s2*v12.x;  acc2[1] += w0s2*v02.y + w1s2*v12.y;
    acc2[2] += w0s2*v02.z + w1s2*v12.z;  acc2[3] += w0s2*v02.w + w1s2*v12.w;
  }
  if (e < end){
    const int s0 = srcs[e];
    float w0 = 0.f;
    if (hl){
      w0 = __expf(leaky(el[s0*10+lane]+erh) - m);
      s += w0;
    }
    const float* r0 = f1 + (size_t)s0*640;
    float4 v00 = *reinterpret_cast<const float4*>(r0 + 4*lane);
    float4 v01 = *reinterpret_cast<const float4*>(r0 + 256 + 4*lane);
    float4 v02 = make_float4(0.f,0.f,0.f,0.f);
    if (lane < 32) v02 = *reinterpret_cast<const float4*>(r0 + 512 + 4*lane);
    float w0s0 = __shfl(w0,hm0,64), w0s1 = __shfl(w0,hm1,64), w0s2 = __shfl(w0,hm2,64);
    acc0[0] += w0s0*v00.x;  acc0[1] += w0s0*v00.y;  acc0[2] += w0s0*v00.z;  acc0[3] += w0s0*v00.w;
    acc1[0] += w0s1*v01.x;  acc1[1] += w0s1*v01.y;  acc1[2] += w0s1*v01.z;  acc1[3] += w0s1*v01.w;
    acc2[0] += w0s2*v02.x;  acc2[1] += w0s2*v02.y;  acc2[2] += w0s2*v02.z;  acc2[3] += w0s2*v02.w;
  }
  // epilogue: normalize per head, +bias, relu, then head-sum via LDS
  const float rs = (hl && s > 0.f) ? 1.f/s : 0.f;
  const float r0v = __shfl(rs,hm0,64), r1v = __shfl(rs,hm1,64), r2v = __shfl(rs,hm2,64);
  float4 bb0 = *reinterpret_cast<const float4*>(b1 + 4*lane);
  float4 bb1 = *reinterpret_cast<const float4*>(b1 + 256 + 4*lane);
  float4 bb2 = make_float4(0.f,0.f,0.f,0.f);
  if (lane < 32) bb2 = *reinterpret_cast<const float4*>(b1 + 512 + 4*lane);
  float* sw = sh + wid*640;
  float4 o0, o1, o2;
  o0.x = fmaxf(acc0[0]*r0v + bb0.x, 0.f);  o0.y = fmaxf(acc0[1]*r0v + bb0.y, 0.f);
  o0.z = fmaxf(acc0[2]*r0v + bb0.z, 0.f);  o0.w = fmaxf(acc0[3]*r0v + bb0.w, 0.f);
  o1.x = fmaxf(acc1[0]*r1v + bb1.x, 0.f);  o1.y = fmaxf(acc1[1]*r1v + bb1.y, 0.f);
  o1.z = fmaxf(acc1[2]*r1v + bb1.z, 0.f);  o1.w = fmaxf(acc1[3]*r1v + bb1.w, 0.f);
  o2.x = fmaxf(acc2[0]*r2v + bb2.x, 0.f);  o2.y = fmaxf(acc2[1]*r2v + bb2.y, 0.f);
  o2.z = fmaxf(acc2[2]*r2v + bb2.z, 0.f);  o2.w = fmaxf(acc2[3]*r2v + bb2.w, 0.f);
  *reinterpret_cast<float4*>(sw + 4*lane)       = o0;
  *reinterpret_cast<float4*>(sw + 256 + 4*lane) = o1;
  if (lane < 32) *reinterpret_cast<float4*>(sw + 512 + 4*lane) = o2;
  asm volatile("s_waitcnt lgkmcnt(0)" ::: "memory");  // same-wave LDS write->read
  float o = 0.f;
  #pragma unroll
  for (int h=0;h<10;h++) o += sw[h*64 + lane];
  hout[(size_t)n*64 + lane] = o;
}

// ---------------- layer2 edge aggregation: one wave per node, H=1, D=128 ----------------
__global__ __launch_bounds__(256) void k_edge2(const float* __restrict__ f2, const float* __restrict__ el,
                                               const float* __restrict__ er, const int* __restrict__ off,
                                               const int* __restrict__ srcs, const float* __restrict__ b2,
                                               float* __restrict__ h2, int N){
  int n = blockIdx.x*4 + (threadIdx.x>>6);
  int lane = threadIdx.x & 63;
  if (n >= N) return;
  const int beg = off[n], end = off[n+1];
  const float ern = er[n];
  float mx = -INFINITY;
  for (int e=beg+lane; e<end; e+=64) mx = fmaxf(mx, el[srcs[e]]);
  #pragma unroll
  for (int o=32;o>0;o>>=1) mx = fmaxf(mx, __shfl_xor(mx,o,64));
  const float m = leaky(mx + ern);
  float s = 0.f, ax = 0.f, ay = 0.f;
  int e = beg;
  for (; e+1<end; e+=2){
    int s0 = srcs[e], s1 = srcs[e+1];
    float w0 = __expf(leaky(el[s0]+ern) - m);
    float w1 = __expf(leaky(el[s1]+ern) - m);
    s += w0 + w1;
    float2 p0 = *reinterpret_cast<const float2*>(f2 + (size_t)s0*128 + 2*lane);
    float2 p1 = *reinterpret_cast<const float2*>(f2 + (size_t)s1*128 + 2*lane);
    ax += w0*p0.x + w1*p1.x;
    ay += w0*p0.y + w1*p1.y;
  }
  if (e < end){
    int s0 = srcs[e];
    float w0 = __expf(leaky(el[s0]+ern) - m);
    s += w0;
    float2 p0 = *reinterpret_cast<const float2*>(f2 + (size_t)s0*128 + 2*lane);
    ax += w0*p0.x;
    ay += w0*p0.y;
  }
  const float rs = (s > 0.f) ? 1.f/s : 0.f;
  float2 bb = *reinterpret_cast<const float2*>(b2 + 2*lane);
  float2 o;
  o.x = fmaxf(ax*rs + bb.x, 0.f);
  o.y = fmaxf(ay*rs + bb.y, 0.f);
  *reinterpret_cast<float2*>(h2 + (size_t)n*128 + 2*lane) = o;
}

// ---------------- per-graph max readout + 2-layer MLP ----------------
__device__ __forceinline__ int lowerb(const int* a, int n, int v){
  int lo=0, hi=n;
  while (lo < hi){ int mid=(lo+hi)>>1; if (a[mid] < v) lo=mid+1; else hi=mid; }
  return lo;
}

__global__ __launch_bounds__(128) void k_readout(const float* __restrict__ h2, const int* __restrict__ gid,
                                                 const float* __restrict__ lw1, const float* __restrict__ lb1,
                                                 const float* __restrict__ lw2, const float* __restrict__ lb2,
                                                 float* __restrict__ out, int N){
  int b = blockIdx.x, t = threadIdx.x;   // t = channel 0..127
  int lo = lowerb(gid, N, b), hi = lowerb(gid, N, b+1);
  float mx = -INFINITY;
  for (int n=lo; n<hi; ++n) mx = fmaxf(mx, h2[(size_t)n*128 + t]);
  if (hi == lo) mx = 0.f;   // empty-graph / isfinite safety
  __shared__ float gs[128];
  __shared__ float ys[128];
  gs[t] = mx;
  __syncthreads();
  float y = lb1[t];
  for (int k=0;k<128;k++) y += gs[k]*lw1[k*128 + t];
  y = fmaxf(y, 0.f);
  ys[t] = y * lw2[t];
  __syncthreads();
  for (int o=64;o>0;o>>=1){
    if (t < o) ys[t] += ys[t+o];
    __syncthreads();
  }
  if (t == 0) out[b] = fmaxf(ys[0] + lb2[0], 0.f);
}

extern "C" void kernel_launch(void* const* d_in, const int* in_sizes, int n_in,
                              void* d_out, int out_size, void* d_ws, size_t ws_size,
                              hipStream_t stream){
  const float* x   = (const float*)d_in[0];
  const int*   src = (const int*)d_in[1];
  const int*   dst = (const int*)d_in[2];
  const int*   gid = (const int*)d_in[3];
  const float* W1  = (const float*)d_in[4];
  const float* al1 = (const float*)d_in[5];
  const float* ar1 = (const float*)d_in[6];
  const float* b1  = (const float*)d_in[7];
  const float* W2  = (const float*)d_in[8];
  const float* al2 = (const float*)d_in[9];
  const float* ar2 = (const float*)d_in[10];
  const float* b2  = (const float*)d_in[11];
  const float* lw1 = (const float*)d_in[12];
  const float* lb1 = (const float*)d_in[13];
  const float* lw2 = (const float*)d_in[14];
  const float* lb2 = (const float*)d_in[15];
  float* out = (float*)d_out;

  const int N = in_sizes[0] / 64;
  const int E = in_sizes[1];
  const int G = out_size;

  char* w = (char*)d_ws;
  size_t p = 0;
  auto alloc = [&](size_t bytes)->char*{ char* r = w + p; p += (bytes + 255) & ~size_t(255); return r; };
  int*   deg  = (int*)alloc((size_t)N*4);
  int*   off  = (int*)alloc((size_t)(N+1)*4);
  int*   cur  = (int*)alloc((size_t)N*4);
  int*   srcs = (int*)alloc((size_t)E*4);
  float* el1  = (float*)alloc((size_t)N*10*4);
  float* er1  = (float*)alloc((size_t)N*10*4);
  float* h1   = (float*)alloc((size_t)N*64*4);
  float* f1   = (float*)alloc((size_t)N*640*4);
  // layer-2 buffers alias the (dead-after-edge1) f1 region
  float* f2  = f1;                    // N*128 floats
  float* h2  = f1 + (size_t)N*128;    // N*128 floats
  float* el2 = el1;
  float* er2 = er1;

  const int nwB = (N + 3) / 4;   // 4 waves (nodes) per 256-thread block

  k_zero   <<<dim3((N+255)/256), dim3(256), 0, stream>>>(deg, N);
  k_hist   <<<dim3((E+255)/256), dim3(256), 0, stream>>>(dst, deg, E);
  k_scan   <<<dim3(1),           dim3(1024),0, stream>>>(deg, off, cur, N);
  k_scatter<<<dim3((E+255)/256), dim3(256), 0, stream>>>(src, dst, cur, srcs, E);

  // layer 1: GEMM with fused attention-coef epilogue
  k_gemm64 <<<dim3((N+63)/64, 10), dim3(256), 0, stream>>>(x, W1, f1, N, 640, al1, ar1, el1, er1, 10);
  k_edge1  <<<dim3(nwB), dim3(256), 0, stream>>>(f1, el1, er1, off, srcs, b1, h1, N);

  // layer 2
  k_gemm64 <<<dim3((N+63)/64, 2), dim3(256), 0, stream>>>(h1, W2, f2, N, 128,
                                                          nullptr, nullptr, nullptr, nullptr, 1);
  k_coef2  <<<dim3(nwB), dim3(256), 0, stream>>>(f2, al2, ar2, el2, er2, N);
  k_edge2  <<<dim3(nwB), dim3(256), 0, stream>>>(f2, el2, er2, off, srcs, b2, h2, N);

  k_readout<<<dim3(G), dim3(128), 0, stream>>>(h2, gid, lw1, lb1, lw2, lb2, out, N);
}